// Round 1
// baseline (712.969 us; speedup 1.0000x reference)
//
#include <hip/hip_runtime.h>
#include <math.h>

#define Bn 16
#define Cn 32
#define Hn 128
#define Wn 128
#define HW (Hn*Wn)
#define Rn 8
#define OUTn 32

// ws layout (byte offsets)
#define OFF_POOLED 0u           // 4608 floats
#define OFF_G      18432u       // 9216 floats
#define OFF_KERN   55296u       // 1179648 floats  [b][ro=256][c=32][tap=9]
#define OFF_RSEL   4773888u     // 262144 int
#define OFF_CAT    5822464u     // 16777216 floats [b][64][HW]

// ---------------- stage A: dynamic kernel generation ----------------

__global__ void pool_kernel(const float* __restrict__ in, float* __restrict__ pooled) {
  const int bc = blockIdx.x;                     // b*Cn + c
  const float* img = in + (size_t)bc * HW;
  __shared__ float red[256];
  const int tid = threadIdx.x;
  const int s0[3] = {0, 42, 85};
  const int e0[3] = {43, 86, 128};
  for (int bi = 0; bi < 3; ++bi) {
    for (int bj = 0; bj < 3; ++bj) {
      const int rs = s0[bi], nr = e0[bi] - rs;
      const int cs = s0[bj], nc = e0[bj] - cs;
      const int n = nr * nc;
      float acc = 0.f;
      for (int i = tid; i < n; i += 256) {
        int y = rs + i / nc, x = cs + i % nc;
        acc += img[y * Wn + x];
      }
      red[tid] = acc; __syncthreads();
      for (int st = 128; st > 0; st >>= 1) {
        if (tid < st) red[tid] += red[tid + st];
        __syncthreads();
      }
      if (tid == 0) pooled[bc * 9 + bi * 3 + bj] = red[0] / (float)n;
      __syncthreads();
    }
  }
}

__global__ void g_kernel(const float* __restrict__ pooled, const float* __restrict__ w1,
                         const float* __restrict__ b1, float* __restrict__ g) {
  const int idx = blockIdx.x * 256 + threadIdx.x;   // (b*64 + o64)*9 + bin
  if (idx >= Bn * 64 * 9) return;
  const int bin = idx % 9;
  const int o = (idx / 9) % 64;
  const int b = idx / (9 * 64);
  float acc = b1[o];
  #pragma unroll
  for (int c = 0; c < Cn; ++c)
    acc = fmaf(pooled[(b * Cn + c) * 9 + bin], w1[o * Cn + c], acc);
  g[idx] = 1.f / (1.f + expf(-acc));
}

__global__ void kern_kernel(const float* __restrict__ g, const float* __restrict__ w2,
                            const float* __restrict__ b2, float* __restrict__ kern) {
  const int idx = blockIdx.x * 256 + threadIdx.x;   // ((b*256 + ro)*32 + c)*9 + tap
  if (idx >= Bn * 256 * Cn * 9) return;
  const int tap = idx % 9;
  const int c = (idx / 9) % Cn;
  const int ro = (idx / (9 * Cn)) % 256;
  const int b = idx / (9 * Cn * 256);
  const int r = ro >> 5, u = ro & 31;
  const int o = u * Cn + c;                          // index in [0, C*OUT)
  float acc = b2[r * 1024 + o];
  #pragma unroll
  for (int i = 0; i < 8; ++i)
    acc = fmaf(g[(b * 64 + r * 8 + i) * 9 + tap], w2[(r * 1024 + o) * 8 + i], acc);
  kern[idx] = acc;
}

// ---------------- region selection (argmax of the two guide classifiers) ----------------

__global__ void rsel_kernel(const float* __restrict__ guide,
                            const float* __restrict__ w_spa, const float* __restrict__ b_spa,
                            const float* __restrict__ w_spec, const float* __restrict__ b_spec,
                            int* __restrict__ rsel) {
  const int idx = blockIdx.x * 256 + threadIdx.x;   // b*HW + p
  const int b = idx >> 14;
  const int p = idx & (HW - 1);
  float gv[Cn];
  const float* gp = guide + (size_t)b * Cn * HW + p;
  #pragma unroll
  for (int c = 0; c < Cn; ++c) gv[c] = gp[c * HW];
  int best1 = 0, best2 = 0;
  float bv1 = -1e30f, bv2 = -1e30f;
  for (int r = 0; r < Rn; ++r) {
    float v1 = b_spa[r], v2 = b_spec[r];
    #pragma unroll
    for (int c = 0; c < Cn; ++c) {
      v1 = fmaf(gv[c], w_spa[r * Cn + c], v1);
      v2 = fmaf(gv[c], w_spec[r * Cn + c], v2);
    }
    if (v1 > bv1) { bv1 = v1; best1 = r; }   // strict > keeps FIRST max (jnp.argmax)
    if (v2 > bv2) { bv2 = v2; best2 = r; }
  }
  rsel[idx] = best1 | (best2 << 8);
}

// ---------------- stage B: selected correlation conv ----------------
// block = (b, region r, chunk of 2048 pixels). Compact matching pixels into LDS,
// then each lane computes 32 out-channels with wave-uniform (scalar-loaded) weights.

__global__ __launch_bounds__(256) void stageB_kernel(
    const float* __restrict__ in, const float* __restrict__ kern,
    const int* __restrict__ rsel, float* __restrict__ outcat) {
  const int id = blockIdx.x;
  const int chunk = id & 7, r = (id >> 3) & 7, b = id >> 6;  // chunk fastest -> XCD affinity
  const int pbase = chunk * 2048;
  __shared__ int lcount;
  __shared__ unsigned short list[4096];
  const int tid = threadIdx.x;
  if (tid == 0) lcount = 0;
  __syncthreads();
  const int* rs = rsel + b * HW + pbase;
  for (int i = tid; i < 2048; i += 256) {
    int v = rs[i];
    if ((v & 255) == r) { int k = atomicAdd(&lcount, 1); list[k] = (unsigned short)i; }
    if ((v >> 8) == r)  { int k = atomicAdd(&lcount, 1); list[k] = (unsigned short)(i | 2048); }
  }
  __syncthreads();
  const int cnt = lcount;
  const float* kw = kern + (size_t)(b * 256 + r * 32) * 288;   // [o][c][tap], o stride 288
  const float* inb = in + (size_t)b * Cn * HW;
  for (int e = tid; e < cnt; e += 256) {
    const int ent = list[e];
    const int p = pbase + (ent & 2047);
    const int which = ent >> 11;
    const int y = p >> 7, x = p & 127;
    float acc[32];
    #pragma unroll
    for (int o = 0; o < 32; ++o) acc[o] = 0.f;
    for (int c = 0; c < Cn; ++c) {
      const float* ip = inb + c * HW;
      float patch[9];
      #pragma unroll
      for (int dy = 0; dy < 3; ++dy) {
        const int yy = y + dy - 1;
        const bool vy = (unsigned)yy < (unsigned)Hn;
        #pragma unroll
        for (int dx = 0; dx < 3; ++dx) {
          const int xx = x + dx - 1;
          const bool v = vy && ((unsigned)xx < (unsigned)Wn);
          patch[dy * 3 + dx] = v ? ip[yy * Wn + xx] : 0.f;
        }
      }
      const float* kwc = kw + c * 9;
      #pragma unroll
      for (int o = 0; o < 32; ++o) {
        #pragma unroll
        for (int t = 0; t < 9; ++t)
          acc[o] = fmaf(patch[t], kwc[o * 288 + t], acc[o]);
      }
    }
    float* op = outcat + (size_t)(b * 64 + which * 32) * HW + p;
    #pragma unroll
    for (int o = 0; o < 32; ++o) op[o * HW] = acc[o];
  }
}

// ---------------- stage C: 3x3 fusion conv + bias + residual ----------------

__global__ __launch_bounds__(256) void stageC_kernel(
    const float* __restrict__ outcat, const float* __restrict__ w_f,
    const float* __restrict__ b_f, const float* __restrict__ in,
    float* __restrict__ out) {
  const int id = blockIdx.x;
  const int b = id >> 6, tile = id & 63;
  const int ty = tile >> 3, tx = tile & 7;
  const int y = ty * 16 + (threadIdx.x >> 4);
  const int x = tx * 16 + (threadIdx.x & 15);
  const int p = y * Wn + x;
  float acc[32];
  #pragma unroll
  for (int o = 0; o < 32; ++o) acc[o] = 0.f;
  const float* catb = outcat + (size_t)b * 64 * HW;
  for (int ci = 0; ci < 64; ++ci) {
    const float* ip = catb + (size_t)ci * HW;
    float patch[9];
    #pragma unroll
    for (int dy = 0; dy < 3; ++dy) {
      const int yy = y + dy - 1;
      const bool vy = (unsigned)yy < (unsigned)Hn;
      #pragma unroll
      for (int dx = 0; dx < 3; ++dx) {
        const int xx = x + dx - 1;
        const bool v = vy && ((unsigned)xx < (unsigned)Wn);
        patch[dy * 3 + dx] = v ? ip[yy * Wn + xx] : 0.f;
      }
    }
    #pragma unroll
    for (int o = 0; o < 32; ++o) {
      #pragma unroll
      for (int t = 0; t < 9; ++t)
        acc[o] = fmaf(patch[t], w_f[(o * 64 + ci) * 9 + t], acc[o]);
    }
  }
  #pragma unroll
  for (int o = 0; o < 32; ++o) {
    const size_t oi = (size_t)(b * 32 + o) * HW + p;
    out[oi] = acc[o] + b_f[o] + in[oi];
  }
}

// ---------------- launcher ----------------

extern "C" void kernel_launch(void* const* d_in, const int* in_sizes, int n_in,
                              void* d_out, int out_size, void* d_ws, size_t ws_size,
                              hipStream_t stream) {
  const float* input  = (const float*)d_in[0];
  const float* guide  = (const float*)d_in[1];
  const float* w1     = (const float*)d_in[2];
  const float* b1     = (const float*)d_in[3];
  const float* w2     = (const float*)d_in[4];
  const float* b2     = (const float*)d_in[5];
  const float* w_spa  = (const float*)d_in[6];
  const float* b_spa  = (const float*)d_in[7];
  const float* w_spec = (const float*)d_in[8];
  const float* b_spec = (const float*)d_in[9];
  const float* w_f    = (const float*)d_in[10];
  const float* b_f    = (const float*)d_in[11];
  float* out = (float*)d_out;

  char* ws = (char*)d_ws;
  float* pooled = (float*)(ws + OFF_POOLED);
  float* g      = (float*)(ws + OFF_G);
  float* kern   = (float*)(ws + OFF_KERN);
  int*   rsel   = (int*)(ws + OFF_RSEL);
  float* outcat = (float*)(ws + OFF_CAT);

  pool_kernel<<<Bn * Cn, 256, 0, stream>>>(input, pooled);
  g_kernel<<<(Bn * 64 * 9 + 255) / 256, 256, 0, stream>>>(pooled, w1, b1, g);
  kern_kernel<<<(Bn * 256 * Cn * 9 + 255) / 256, 256, 0, stream>>>(g, w2, b2, kern);
  rsel_kernel<<<Bn * HW / 256, 256, 0, stream>>>(guide, w_spa, b_spa, w_spec, b_spec, rsel);
  stageB_kernel<<<1024, 256, 0, stream>>>(input, kern, rsel, outcat);
  stageC_kernel<<<1024, 256, 0, stream>>>(outcat, w_f, b_f, input, out);
}

// Round 2
// 592.384 us; speedup vs baseline: 1.2036x; 1.2036x over previous
//
#include <hip/hip_runtime.h>
#include <hip/hip_bf16.h>
#include <math.h>

#define Bn 16
#define Cn 32
#define Hn 128
#define Wn 128
#define HW (Hn*Wn)
#define Rn 8
#define OUTn 32

// ws layout (byte offsets)
#define OFF_POOLED 0u            // 4608 f
#define OFF_G      18432u        // 9216 f
#define OFF_KERN   55296u        // 1179648 f  [b][r][tap][c][o]
#define OFF_RSEL   4773888u      // 262144 int
#define OFF_WFT    5822464u      // 18432 f    [tap][ci][o]
#define OFF_INT    5896192u      // 16.7M bf16 [b][p][c]
#define OFF_CAT    22673408u     // 33.5M bf16 [b][p][which][o]   (ends 56.2 MB)

static __device__ __forceinline__ unsigned short f2b(float f) {
  __hip_bfloat16 h = __float2bfloat16(f);
  return *reinterpret_cast<unsigned short*>(&h);
}

// ---------------- stage A: dynamic kernel generation ----------------

__global__ void pool_kernel(const float* __restrict__ in, float* __restrict__ pooled) {
  const int bc = blockIdx.x;                     // b*Cn + c
  const float* img = in + (size_t)bc * HW;
  __shared__ float red[256];
  const int tid = threadIdx.x;
  const int s0[3] = {0, 42, 85};
  const int e0[3] = {43, 86, 128};
  for (int bi = 0; bi < 3; ++bi) {
    for (int bj = 0; bj < 3; ++bj) {
      const int rs = s0[bi], nr = e0[bi] - rs;
      const int cs = s0[bj], nc = e0[bj] - cs;
      const int n = nr * nc;
      float acc = 0.f;
      for (int i = tid; i < n; i += 256) {
        int y = rs + i / nc, x = cs + i % nc;
        acc += img[y * Wn + x];
      }
      red[tid] = acc; __syncthreads();
      for (int st = 128; st > 0; st >>= 1) {
        if (tid < st) red[tid] += red[tid + st];
        __syncthreads();
      }
      if (tid == 0) pooled[bc * 9 + bi * 3 + bj] = red[0] / (float)n;
      __syncthreads();
    }
  }
}

__global__ void g_kernel(const float* __restrict__ pooled, const float* __restrict__ w1,
                         const float* __restrict__ b1, float* __restrict__ g) {
  const int idx = blockIdx.x * 256 + threadIdx.x;   // (b*64 + o64)*9 + bin
  if (idx >= Bn * 64 * 9) return;
  const int bin = idx % 9;
  const int o = (idx / 9) % 64;
  const int b = idx / (9 * 64);
  float acc = b1[o];
  #pragma unroll
  for (int c = 0; c < Cn; ++c)
    acc = fmaf(pooled[(b * Cn + c) * 9 + bin], w1[o * Cn + c], acc);
  g[idx] = 1.f / (1.f + expf(-acc));
}

// kern2 layout: (((b*8 + r)*9 + t)*32 + c)*32 + u
__global__ void kern_kernel(const float* __restrict__ g, const float* __restrict__ w2,
                            const float* __restrict__ b2, float* __restrict__ kern2) {
  const int idx = blockIdx.x * 256 + threadIdx.x;
  if (idx >= Bn * 8 * 9 * 32 * 32) return;
  const int u = idx & 31;
  const int c = (idx >> 5) & 31;
  const int t = (idx >> 10) % 9;
  const int r = (idx / 9216) & 7;
  const int b = idx / (9216 * 8);
  const int j = u * 32 + c;                        // index within C*OUT group
  float acc = b2[r * 1024 + j];
  #pragma unroll
  for (int i = 0; i < 8; ++i)
    acc = fmaf(g[(b * 64 + r * 8 + i) * 9 + t], w2[(r * 1024 + j) * 8 + i], acc);
  kern2[idx] = acc;
}

// wfT layout: (t*64 + ci)*32 + o
__global__ void wf_kernel(const float* __restrict__ w_f, float* __restrict__ wfT) {
  int idx = blockIdx.x * 256 + threadIdx.x;
  if (idx >= 9 * 64 * 32) return;
  int o = idx & 31, ci = (idx >> 5) & 63, t = idx >> 11;
  wfT[idx] = w_f[(o * 64 + ci) * 9 + t];
}

// ---------------- input transpose to channel-last bf16 ----------------

__global__ __launch_bounds__(256) void tr_kernel(const float* __restrict__ in,
                                                 uint4* __restrict__ inT) {
  __shared__ float lds[32][65];
  const int blk = blockIdx.x;          // b*256 + pixel-group
  const int b = blk >> 8;
  const int p0 = (blk & 255) * 64;
  const int tid = threadIdx.x;
  const int pl = tid & 63;
  const int c0 = tid >> 6;             // 0..3
  #pragma unroll
  for (int cc = 0; cc < 8; ++cc) {
    const int c = cc * 4 + c0;
    lds[c][pl] = in[(size_t)(b * 32 + c) * HW + p0 + pl];
  }
  __syncthreads();
  const int pw = tid >> 2;             // 0..63
  const int cg = (tid & 3) * 8;        // 0,8,16,24
  unsigned int w0 = (unsigned)f2b(lds[cg + 0][pw]) | ((unsigned)f2b(lds[cg + 1][pw]) << 16);
  unsigned int w1 = (unsigned)f2b(lds[cg + 2][pw]) | ((unsigned)f2b(lds[cg + 3][pw]) << 16);
  unsigned int w2 = (unsigned)f2b(lds[cg + 4][pw]) | ((unsigned)f2b(lds[cg + 5][pw]) << 16);
  unsigned int w3 = (unsigned)f2b(lds[cg + 6][pw]) | ((unsigned)f2b(lds[cg + 7][pw]) << 16);
  inT[(size_t)(b * HW + p0 + pw) * 4 + (tid & 3)] = make_uint4(w0, w1, w2, w3);
}

// ---------------- region selection ----------------

__global__ void rsel_kernel(const float* __restrict__ guide,
                            const float* __restrict__ w_spa, const float* __restrict__ b_spa,
                            const float* __restrict__ w_spec, const float* __restrict__ b_spec,
                            int* __restrict__ rsel) {
  const int idx = blockIdx.x * 256 + threadIdx.x;   // b*HW + p
  const int b = idx >> 14;
  const int p = idx & (HW - 1);
  float gv[Cn];
  const float* gp = guide + (size_t)b * Cn * HW + p;
  #pragma unroll
  for (int c = 0; c < Cn; ++c) gv[c] = gp[c * HW];
  int best1 = 0, best2 = 0;
  float bv1 = -1e30f, bv2 = -1e30f;
  for (int r = 0; r < Rn; ++r) {
    float v1 = b_spa[r], v2 = b_spec[r];
    #pragma unroll
    for (int c = 0; c < Cn; ++c) {
      v1 = fmaf(gv[c], w_spa[r * Cn + c], v1);
      v2 = fmaf(gv[c], w_spec[r * Cn + c], v2);
    }
    if (v1 > bv1) { bv1 = v1; best1 = r; }   // strict > keeps FIRST max (jnp.argmax)
    if (v2 > bv2) { bv2 = v2; best2 = r; }
  }
  rsel[idx] = best1 | (best2 << 8);
}

// ---------------- stage B: selected correlation conv (channel-last) ----------------

__global__ __launch_bounds__(256) void stageB_kernel(
    const uint4* __restrict__ inT, const float* __restrict__ kern2,
    const int* __restrict__ rsel, uint4* __restrict__ outcatT) {
  const int id = blockIdx.x;
  const int chunk = id & 7, r = (id >> 3) & 7, b = id >> 6;  // chunk fastest -> XCD affinity
  const int pbase = chunk * 2048;
  __shared__ int lcount;
  __shared__ unsigned short list[4096];
  const int tid = threadIdx.x;
  if (tid == 0) lcount = 0;
  __syncthreads();
  const int* rs = rsel + b * HW + pbase;
  for (int i = tid; i < 2048; i += 256) {
    int v = rs[i];
    if ((v & 255) == r) { int k = atomicAdd(&lcount, 1); list[k] = (unsigned short)i; }
    if ((v >> 8) == r)  { int k = atomicAdd(&lcount, 1); list[k] = (unsigned short)(i | 2048); }
  }
  __syncthreads();
  const int cnt = lcount;
  const float* wb = kern2 + (size_t)(b * 8 + r) * 9216;   // [t][c][u]
  const uint4* inb = inT + (size_t)b * HW * 4;            // 4 uint4 per pixel
  for (int e = tid; e < cnt; e += 256) {
    const int ent = list[e];
    const int p = pbase + (ent & 2047);
    const int which = ent >> 11;
    const int y = p >> 7, x = p & 127;
    float acc[32];
    #pragma unroll
    for (int u = 0; u < 32; ++u) acc[u] = 0.f;
    int t = 0;
    #pragma unroll 1
    for (int dy = 0; dy < 3; ++dy) {
      const int yy = y + dy - 1;
      #pragma unroll 1
      for (int dx = 0; dx < 3; ++dx, ++t) {
        const int xx = x + dx - 1;
        const bool valid = ((unsigned)yy < (unsigned)Hn) && ((unsigned)xx < (unsigned)Wn);
        if (valid) {
          const uint4* xp = inb + (size_t)(yy * Wn + xx) * 4;
          float xv[32];
          #pragma unroll
          for (int q = 0; q < 4; ++q) {
            const uint4 vv = xp[q];
            xv[q * 8 + 0] = __uint_as_float(vv.x << 16);
            xv[q * 8 + 1] = __uint_as_float(vv.x & 0xffff0000u);
            xv[q * 8 + 2] = __uint_as_float(vv.y << 16);
            xv[q * 8 + 3] = __uint_as_float(vv.y & 0xffff0000u);
            xv[q * 8 + 4] = __uint_as_float(vv.z << 16);
            xv[q * 8 + 5] = __uint_as_float(vv.z & 0xffff0000u);
            xv[q * 8 + 6] = __uint_as_float(vv.w << 16);
            xv[q * 8 + 7] = __uint_as_float(vv.w & 0xffff0000u);
          }
          const float* wt = wb + t * 1024;
          #pragma unroll
          for (int c = 0; c < 32; ++c) {
            #pragma unroll
            for (int u = 0; u < 32; ++u)
              acc[u] = fmaf(xv[c], wt[c * 32 + u], acc[u]);
          }
        }
      }
    }
    unsigned int ob[16];
    #pragma unroll
    for (int q = 0; q < 16; ++q)
      ob[q] = (unsigned)f2b(acc[q * 2]) | ((unsigned)f2b(acc[q * 2 + 1]) << 16);
    uint4* op = outcatT + ((size_t)(b * HW + p) * 2 + which) * 4;
    #pragma unroll
    for (int q = 0; q < 4; ++q)
      op[q] = make_uint4(ob[q * 4], ob[q * 4 + 1], ob[q * 4 + 2], ob[q * 4 + 3]);
  }
}

// ---------------- stage C: 3x3 fusion conv + bias + residual ----------------

__global__ __launch_bounds__(256) void stageC_kernel(
    const uint4* __restrict__ outcatT, const float* __restrict__ wfT,
    const float* __restrict__ b_f, const float* __restrict__ in,
    float* __restrict__ out) {
  const int id = blockIdx.x;
  const int b = id >> 6, tile = id & 63;
  const int ty = tile >> 3, tx = tile & 7;
  const int y = ty * 16 + (threadIdx.x >> 4);
  const int x = tx * 16 + (threadIdx.x & 15);
  const int p = y * Wn + x;
  float acc[32];
  #pragma unroll
  for (int o = 0; o < 32; ++o) acc[o] = 0.f;
  const uint4* catb = outcatT + (size_t)b * HW * 8;   // 8 uint4 per pixel (64 bf16)
  int t = 0;
  #pragma unroll 1
  for (int dy = 0; dy < 3; ++dy) {
    const int yy = y + dy - 1;
    #pragma unroll 1
    for (int dx = 0; dx < 3; ++dx, ++t) {
      const int xx = x + dx - 1;
      const bool valid = ((unsigned)yy < (unsigned)Hn) && ((unsigned)xx < (unsigned)Wn);
      if (!valid) continue;
      const uint4* xp = catb + (size_t)(yy * Wn + xx) * 8;
      #pragma unroll 1
      for (int half = 0; half < 2; ++half) {
        float xv[32];
        #pragma unroll
        for (int q = 0; q < 4; ++q) {
          const uint4 vv = xp[half * 4 + q];
          xv[q * 8 + 0] = __uint_as_float(vv.x << 16);
          xv[q * 8 + 1] = __uint_as_float(vv.x & 0xffff0000u);
          xv[q * 8 + 2] = __uint_as_float(vv.y << 16);
          xv[q * 8 + 3] = __uint_as_float(vv.y & 0xffff0000u);
          xv[q * 8 + 4] = __uint_as_float(vv.z << 16);
          xv[q * 8 + 5] = __uint_as_float(vv.z & 0xffff0000u);
          xv[q * 8 + 6] = __uint_as_float(vv.w << 16);
          xv[q * 8 + 7] = __uint_as_float(vv.w & 0xffff0000u);
        }
        const float* wt = wfT + t * 2048 + half * 1024;
        #pragma unroll
        for (int c = 0; c < 32; ++c) {
          #pragma unroll
          for (int o = 0; o < 32; ++o)
            acc[o] = fmaf(xv[c], wt[c * 32 + o], acc[o]);
        }
      }
    }
  }
  #pragma unroll
  for (int o = 0; o < 32; ++o) {
    const size_t oi = (size_t)(b * 32 + o) * HW + p;
    out[oi] = acc[o] + b_f[o] + in[oi];
  }
}

// ---------------- launcher ----------------

extern "C" void kernel_launch(void* const* d_in, const int* in_sizes, int n_in,
                              void* d_out, int out_size, void* d_ws, size_t ws_size,
                              hipStream_t stream) {
  const float* input  = (const float*)d_in[0];
  const float* guide  = (const float*)d_in[1];
  const float* w1     = (const float*)d_in[2];
  const float* b1     = (const float*)d_in[3];
  const float* w2     = (const float*)d_in[4];
  const float* b2     = (const float*)d_in[5];
  const float* w_spa  = (const float*)d_in[6];
  const float* b_spa  = (const float*)d_in[7];
  const float* w_spec = (const float*)d_in[8];
  const float* b_spec = (const float*)d_in[9];
  const float* w_f    = (const float*)d_in[10];
  const float* b_f    = (const float*)d_in[11];
  float* out = (float*)d_out;

  char* ws = (char*)d_ws;
  float* pooled = (float*)(ws + OFF_POOLED);
  float* g      = (float*)(ws + OFF_G);
  float* kern2  = (float*)(ws + OFF_KERN);
  int*   rsel   = (int*)(ws + OFF_RSEL);
  float* wfT    = (float*)(ws + OFF_WFT);
  uint4* inT    = (uint4*)(ws + OFF_INT);
  uint4* outcat = (uint4*)(ws + OFF_CAT);

  pool_kernel<<<Bn * Cn, 256, 0, stream>>>(input, pooled);
  g_kernel<<<(Bn * 64 * 9 + 255) / 256, 256, 0, stream>>>(pooled, w1, b1, g);
  kern_kernel<<<(Bn * 8 * 9 * 1024 + 255) / 256, 256, 0, stream>>>(g, w2, b2, kern2);
  wf_kernel<<<(9 * 64 * 32 + 255) / 256, 256, 0, stream>>>(w_f, wfT);
  tr_kernel<<<Bn * 256, 256, 0, stream>>>(input, inT);
  rsel_kernel<<<Bn * HW / 256, 256, 0, stream>>>(guide, w_spa, b_spa, w_spec, b_spec, rsel);
  stageB_kernel<<<1024, 256, 0, stream>>>(inT, kern2, rsel, outcat);
  stageC_kernel<<<1024, 256, 0, stream>>>(outcat, wfT, b_f, input, out);
}

// Round 3
// 271.540 us; speedup vs baseline: 2.6257x; 2.1816x over previous
//
#include <hip/hip_runtime.h>
#include <hip/hip_bf16.h>
#include <math.h>

#define Bn 16
#define Cn 32
#define Hn 128
#define Wn 128
#define HW (Hn*Wn)
#define Rn 8
#define OUTn 32
#define PW 130           // padded width/height (1-px halo)

// ws layout (byte offsets, all 16B-aligned)
#define OFF_POOLED 0u            // 4608 f
#define OFF_G      18432u        // 9216 f
#define OFF_KERNA  55296u        // 1179648 bf16  A-frag layout [b][r][t*2+h][kg][m][j]
#define OFF_WFA    2414592u      // 18432 bf16    A-frag layout [kb*2+h][kg][m][j]
#define OFF_RSEL   2451456u      // 262144 int
#define OFF_INTP   3500032u      // 16*16900 px * 64B  bf16 channel-last, padded
#define OFF_CATP   20805632u     // 16*16900 px * 128B bf16 channel-last, padded
// ends 55,416,832

typedef __attribute__((ext_vector_type(8))) short short8;
typedef __attribute__((ext_vector_type(4))) float floatx4;

static __device__ __forceinline__ unsigned short f2b(float f) {
  __hip_bfloat16 h = __float2bfloat16(f);
  return *reinterpret_cast<unsigned short*>(&h);
}

// ---------------- stage A: dynamic kernel generation ----------------

__global__ void pool_kernel(const float* __restrict__ in, float* __restrict__ pooled) {
  const int bc = blockIdx.x;                     // b*Cn + c
  const float* img = in + (size_t)bc * HW;
  __shared__ float red[256];
  const int tid = threadIdx.x;
  const int s0[3] = {0, 42, 85};
  const int e0[3] = {43, 86, 128};
  for (int bi = 0; bi < 3; ++bi) {
    for (int bj = 0; bj < 3; ++bj) {
      const int rs = s0[bi], nr = e0[bi] - rs;
      const int cs = s0[bj], nc = e0[bj] - cs;
      const int n = nr * nc;
      float acc = 0.f;
      for (int i = tid; i < n; i += 256) {
        int y = rs + i / nc, x = cs + i % nc;
        acc += img[y * Wn + x];
      }
      red[tid] = acc; __syncthreads();
      for (int st = 128; st > 0; st >>= 1) {
        if (tid < st) red[tid] += red[tid + st];
        __syncthreads();
      }
      if (tid == 0) pooled[bc * 9 + bi * 3 + bj] = red[0] / (float)n;
      __syncthreads();
    }
  }
}

__global__ void g_kernel(const float* __restrict__ pooled, const float* __restrict__ w1,
                         const float* __restrict__ b1, float* __restrict__ g) {
  const int idx = blockIdx.x * 256 + threadIdx.x;   // (b*64 + o64)*9 + bin
  if (idx >= Bn * 64 * 9) return;
  const int bin = idx % 9;
  const int o = (idx / 9) % 64;
  const int b = idx / (9 * 64);
  float acc = b1[o];
  #pragma unroll
  for (int c = 0; c < Cn; ++c)
    acc = fmaf(pooled[(b * Cn + c) * 9 + bin], w1[o * Cn + c], acc);
  g[idx] = 1.f / (1.f + expf(-acc));
}

// kernA: per (b,r): 18 fragments (t*2+h), each [kg(4)][m(16)][j(8)] bf16.
// value(b,r,t,h,kg,m,j) = kern(b, r, tap=t, c=kg*8+j, u=h*16+m)
__global__ void kern_kernel(const float* __restrict__ g, const float* __restrict__ w2,
                            const float* __restrict__ b2, short* __restrict__ kernA) {
  const int idx = blockIdx.x * 256 + threadIdx.x;
  if (idx >= Bn * 8 * 9 * 1024) return;
  const int j  = idx & 7;
  const int m  = (idx >> 3) & 15;
  const int kg = (idx >> 7) & 3;
  const int h  = (idx >> 9) & 1;
  const int t  = (idx >> 10) % 9;
  const int br = idx / 9216;
  const int r = br & 7, b = br >> 3;
  const int c = kg * 8 + j;
  const int u = h * 16 + m;
  const int jidx = u * 32 + c;                     // index within C*OUT group
  float acc = b2[r * 1024 + jidx];
  #pragma unroll
  for (int i = 0; i < 8; ++i)
    acc = fmaf(g[(b * 64 + r * 8 + i) * 9 + t], w2[(r * 1024 + jidx) * 8 + i], acc);
  kernA[idx] = (short)f2b(acc);
}

// wfA: 18 K-blocks (kb = tap*2+chalf) x 2 o-halves, each [kg][m][j] bf16.
__global__ void wf_kernel(const float* __restrict__ w_f, short* __restrict__ wfA) {
  int idx = blockIdx.x * 256 + threadIdx.x;
  if (idx >= 18432) return;
  const int j  = idx & 7;
  const int m  = (idx >> 3) & 15;
  const int kg = (idx >> 7) & 3;
  const int h  = (idx >> 9) & 1;
  const int kb = idx >> 10;        // 0..17
  const int tap = kb >> 1, ch = kb & 1;
  const int ci = ch * 32 + kg * 8 + j;
  const int o = h * 16 + m;
  wfA[idx] = (short)f2b(w_f[(o * 64 + ci) * 9 + tap]);
}

// ---------------- input transpose to padded channel-last bf16 ----------------

__global__ __launch_bounds__(256) void tr_kernel(const float* __restrict__ in,
                                                 uint4* __restrict__ inTp) {
  __shared__ float lds[32][65];
  const int blk = blockIdx.x;          // b*256 + pixel-group
  const int b = blk >> 8;
  const int p0 = (blk & 255) * 64;
  const int tid = threadIdx.x;
  const int pl = tid & 63;
  const int c0 = tid >> 6;             // 0..3
  #pragma unroll
  for (int cc = 0; cc < 8; ++cc) {
    const int c = cc * 4 + c0;
    lds[c][pl] = in[(size_t)(b * 32 + c) * HW + p0 + pl];
  }
  __syncthreads();
  const int pw = tid >> 2;             // 0..63
  const int cg = (tid & 3) * 8;        // 0,8,16,24
  unsigned int w0 = (unsigned)f2b(lds[cg + 0][pw]) | ((unsigned)f2b(lds[cg + 1][pw]) << 16);
  unsigned int w1 = (unsigned)f2b(lds[cg + 2][pw]) | ((unsigned)f2b(lds[cg + 3][pw]) << 16);
  unsigned int w2 = (unsigned)f2b(lds[cg + 4][pw]) | ((unsigned)f2b(lds[cg + 5][pw]) << 16);
  unsigned int w3 = (unsigned)f2b(lds[cg + 6][pw]) | ((unsigned)f2b(lds[cg + 7][pw]) << 16);
  const int p = p0 + pw;
  const int y = p >> 7, x = p & 127;
  const size_t pp = (size_t)(b * PW + y + 1) * PW + (x + 1);
  inTp[pp * 4 + (tid & 3)] = make_uint4(w0, w1, w2, w3);
}

// ---------------- region selection ----------------

__global__ void rsel_kernel(const float* __restrict__ guide,
                            const float* __restrict__ w_spa, const float* __restrict__ b_spa,
                            const float* __restrict__ w_spec, const float* __restrict__ b_spec,
                            int* __restrict__ rsel) {
  const int idx = blockIdx.x * 256 + threadIdx.x;   // b*HW + p
  const int b = idx >> 14;
  const int p = idx & (HW - 1);
  float gv[Cn];
  const float* gp = guide + (size_t)b * Cn * HW + p;
  #pragma unroll
  for (int c = 0; c < Cn; ++c) gv[c] = gp[c * HW];
  int best1 = 0, best2 = 0;
  float bv1 = -1e30f, bv2 = -1e30f;
  for (int r = 0; r < Rn; ++r) {
    float v1 = b_spa[r], v2 = b_spec[r];
    #pragma unroll
    for (int c = 0; c < Cn; ++c) {
      v1 = fmaf(gv[c], w_spa[r * Cn + c], v1);
      v2 = fmaf(gv[c], w_spec[r * Cn + c], v2);
    }
    if (v1 > bv1) { bv1 = v1; best1 = r; }   // strict > keeps FIRST max (jnp.argmax)
    if (v2 > bv2) { bv2 = v2; best2 = r; }
  }
  rsel[idx] = best1 | (best2 << 8);
}

// ---------------- stage B: selected correlation conv via MFMA ----------------
// C[o(32), entry(16)] per group; A = generated weights, B = input pixels.

__global__ __launch_bounds__(256) void stageB_kernel(
    const char* __restrict__ inTp, const short* __restrict__ kernA,
    const int* __restrict__ rsel, char* __restrict__ catp) {
  const int id = blockIdx.x;
  const int chunk = id & 7, r = (id >> 3) & 7, b = id >> 6;  // chunk fastest -> XCD affinity
  const int pbase = chunk * 2048;
  __shared__ int lcount;
  __shared__ unsigned short list[4096];
  const int tid = threadIdx.x;
  if (tid == 0) lcount = 0;
  __syncthreads();
  const int* rs = rsel + b * HW + pbase;
  for (int i = tid; i < 2048; i += 256) {
    int v = rs[i];
    if ((v & 255) == r) { int k = atomicAdd(&lcount, 1); list[k] = (unsigned short)i; }
    if ((v >> 8) == r)  { int k = atomicAdd(&lcount, 1); list[k] = (unsigned short)(i | 2048); }
  }
  __syncthreads();
  const int cnt = lcount;
  const int lane = tid & 63, wid = tid >> 6;
  const int l15 = lane & 15, kg = lane >> 4;

  // preload the 18 weight A-fragments (uniform per block)
  short8 aw[18];
  {
    const short* kb = kernA + (size_t)(b * 8 + r) * 18 * 512;
    #pragma unroll
    for (int f = 0; f < 18; ++f)
      aw[f] = *(const short8*)(kb + f * 512 + kg * 128 + l15 * 8);
  }

  for (int g = wid; g * 16 < cnt; g += 4) {
    const int e16 = g * 16 + l15;
    const bool ev = e16 < cnt;
    const int ent = list[ev ? e16 : 0];
    const int p = pbase + (ent & 2047);
    const int which = ent >> 11;
    const int y = p >> 7, x = p & 127;
    const size_t pp = (size_t)(b * PW + y + 1) * PW + (x + 1);
    const char* base = inTp + pp * 64 + kg * 16;
    floatx4 acc0 = {0.f, 0.f, 0.f, 0.f}, acc1 = {0.f, 0.f, 0.f, 0.f};
    #pragma unroll
    for (int t = 0; t < 9; ++t) {
      const int dy = t / 3 - 1, dx = t % 3 - 1;
      const short8 bx = *(const short8*)(base + (dy * PW + dx) * 64);
      acc0 = __builtin_amdgcn_mfma_f32_16x16x32_bf16(aw[t * 2 + 0], bx, acc0, 0, 0, 0);
      acc1 = __builtin_amdgcn_mfma_f32_16x16x32_bf16(aw[t * 2 + 1], bx, acc1, 0, 0, 0);
    }
    if (ev) {
      char* op = catp + pp * 128 + which * 64 + kg * 8;
      uint2 v0, v1;
      v0.x = (unsigned)f2b(acc0[0]) | ((unsigned)f2b(acc0[1]) << 16);
      v0.y = (unsigned)f2b(acc0[2]) | ((unsigned)f2b(acc0[3]) << 16);
      v1.x = (unsigned)f2b(acc1[0]) | ((unsigned)f2b(acc1[1]) << 16);
      v1.y = (unsigned)f2b(acc1[2]) | ((unsigned)f2b(acc1[3]) << 16);
      *(uint2*)op = v0;
      *(uint2*)(op + 32) = v1;
    }
  }
}

// ---------------- stage C: fusion conv via MFMA + bias + residual ----------------

__global__ __launch_bounds__(256) void stageC_kernel(
    const char* __restrict__ catp, const short* __restrict__ wfA,
    const float* __restrict__ b_f, const float* __restrict__ in,
    float* __restrict__ out) {
  __shared__ short lwf[18432];
  const int tid = threadIdx.x;
  {
    const uint4* src = (const uint4*)wfA;
    uint4* dst = (uint4*)lwf;
    #pragma unroll
    for (int i = 0; i < 9; ++i)
      dst[i * 256 + tid] = src[i * 256 + tid];
  }
  __syncthreads();
  const int id = blockIdx.x;
  const int b = id >> 6, seg = id & 63;
  const int lane = tid & 63, wid = tid >> 6;
  const int l15 = lane & 15, kg = lane >> 4;
  const int pix = seg * 256 + wid * 64 + l15;     // + q*16

  const char* bq[4];
  #pragma unroll
  for (int q = 0; q < 4; ++q) {
    const int p = pix + q * 16;
    const int y = p >> 7, x = p & 127;
    bq[q] = catp + ((size_t)(b * PW + y + 1) * PW + (x + 1)) * 128 + kg * 16;
  }
  floatx4 acc[2][4] = {};
  #pragma unroll 1
  for (int kb = 0; kb < 18; ++kb) {
    const int tap = kb >> 1, ch = kb & 1;
    const int dy = tap / 3 - 1, dx = tap % 3 - 1;
    const int goff = (dy * PW + dx) * 128 + ch * 64;
    const short8 a0 = *(const short8*)&lwf[(kb * 2 + 0) * 512 + kg * 128 + l15 * 8];
    const short8 a1 = *(const short8*)&lwf[(kb * 2 + 1) * 512 + kg * 128 + l15 * 8];
    #pragma unroll
    for (int q = 0; q < 4; ++q) {
      const short8 bx = *(const short8*)(bq[q] + goff);
      acc[0][q] = __builtin_amdgcn_mfma_f32_16x16x32_bf16(a0, bx, acc[0][q], 0, 0, 0);
      acc[1][q] = __builtin_amdgcn_mfma_f32_16x16x32_bf16(a1, bx, acc[1][q], 0, 0, 0);
    }
  }
  #pragma unroll
  for (int h = 0; h < 2; ++h) {
    const int o0 = h * 16 + kg * 4;
    #pragma unroll
    for (int q = 0; q < 4; ++q) {
      const int p = pix + q * 16;
      #pragma unroll
      for (int reg = 0; reg < 4; ++reg) {
        const size_t oi = (size_t)(b * 32 + o0 + reg) * HW + p;
        out[oi] = acc[h][q][reg] + b_f[o0 + reg] + in[oi];
      }
    }
  }
}

// ---------------- launcher ----------------

extern "C" void kernel_launch(void* const* d_in, const int* in_sizes, int n_in,
                              void* d_out, int out_size, void* d_ws, size_t ws_size,
                              hipStream_t stream) {
  const float* input  = (const float*)d_in[0];
  const float* guide  = (const float*)d_in[1];
  const float* w1     = (const float*)d_in[2];
  const float* b1     = (const float*)d_in[3];
  const float* w2     = (const float*)d_in[4];
  const float* b2     = (const float*)d_in[5];
  const float* w_spa  = (const float*)d_in[6];
  const float* b_spa  = (const float*)d_in[7];
  const float* w_spec = (const float*)d_in[8];
  const float* b_spec = (const float*)d_in[9];
  const float* w_f    = (const float*)d_in[10];
  const float* b_f    = (const float*)d_in[11];
  float* out = (float*)d_out;

  char* ws = (char*)d_ws;
  float* pooled = (float*)(ws + OFF_POOLED);
  float* g      = (float*)(ws + OFF_G);
  short* kernA  = (short*)(ws + OFF_KERNA);
  short* wfA    = (short*)(ws + OFF_WFA);
  int*   rsel   = (int*)(ws + OFF_RSEL);
  uint4* inTp   = (uint4*)(ws + OFF_INTP);
  char*  catp   = (char*)(ws + OFF_CATP);

  // zero padded buffers (halo must be 0; ws is re-poisoned each call)
  hipMemsetAsync(ws + OFF_INTP, 0, 17305600u + 34611200u, stream);

  pool_kernel<<<Bn * Cn, 256, 0, stream>>>(input, pooled);
  g_kernel<<<(Bn * 64 * 9 + 255) / 256, 256, 0, stream>>>(pooled, w1, b1, g);
  kern_kernel<<<Bn * 8 * 9 * 1024 / 256, 256, 0, stream>>>(g, w2, b2, kernA);
  wf_kernel<<<72, 256, 0, stream>>>(w_f, wfA);
  tr_kernel<<<Bn * 256, 256, 0, stream>>>(input, inTp);
  rsel_kernel<<<Bn * HW / 256, 256, 0, stream>>>(guide, w_spa, b_spa, w_spec, b_spec, rsel);
  stageB_kernel<<<1024, 256, 0, stream>>>((const char*)inTp, kernA, rsel, catp);
  stageC_kernel<<<1024, 256, 0, stream>>>(catp, wfA, b_f, input, out);
}

// Round 4
// 252.931 us; speedup vs baseline: 2.8188x; 1.0736x over previous
//
#include <hip/hip_runtime.h>
#include <hip/hip_bf16.h>
#include <math.h>

#define Bn 16
#define Cn 32
#define Hn 128
#define Wn 128
#define HW (Hn*Wn)
#define Rn 8
#define OUTn 32
#define PW 130           // padded width/height (1-px halo)

// ws layout (byte offsets, all 16B-aligned)
#define OFF_POOLED 0u            // 4608 f
#define OFF_G      18432u        // 9216 f
#define OFF_KERNA  55296u        // 1179648 bf16  A-frag layout [b][r][t*2+h][kg][m][j]
#define OFF_WFA    2414592u      // 18432 bf16    A-frag layout [kb*2+h][kg][m][j]
#define OFF_RSEL   2451456u      // 262144 int
#define OFF_INTP   3500032u      // 16*16900 px * 64B  bf16 channel-last, padded
#define OFF_CATP   20805632u     // 16*16900 px * 128B bf16 channel-last, padded
// ends 55,416,832

typedef __attribute__((ext_vector_type(8))) short short8;
typedef __attribute__((ext_vector_type(4))) float floatx4;

static __device__ __forceinline__ unsigned short f2b(float f) {
  __hip_bfloat16 h = __float2bfloat16(f);
  return *reinterpret_cast<unsigned short*>(&h);
}

// ---------------- stage A: dynamic kernel generation ----------------

// one wave per (b, c, bin): no LDS, no barriers
__global__ __launch_bounds__(64) void pool_kernel(const float* __restrict__ in,
                                                  float* __restrict__ pooled) {
  const int blk = blockIdx.x;          // bc*9 + bin
  const int bin = blk % 9, bc = blk / 9;
  const int bi = bin / 3, bj = bin % 3;
  const int s0[3] = {0, 42, 85};
  const int e0[3] = {43, 86, 128};
  const int rs = s0[bi], re = e0[bi];
  const int cs = s0[bj], ce = e0[bj];
  const int n = (re - rs) * (ce - cs);
  const float* img = in + (size_t)bc * HW;
  float acc = 0.f;
  for (int y = rs; y < re; ++y)
    for (int x = cs + (int)threadIdx.x; x < ce; x += 64)
      acc += img[y * Wn + x];
  #pragma unroll
  for (int off = 32; off > 0; off >>= 1) acc += __shfl_down(acc, off, 64);
  if (threadIdx.x == 0) pooled[bc * 9 + bin] = acc / (float)n;
}

__global__ void g_kernel(const float* __restrict__ pooled, const float* __restrict__ w1,
                         const float* __restrict__ b1, float* __restrict__ g) {
  const int idx = blockIdx.x * 256 + threadIdx.x;   // (b*64 + o64)*9 + bin
  if (idx >= Bn * 64 * 9) return;
  const int bin = idx % 9;
  const int o = (idx / 9) % 64;
  const int b = idx / (9 * 64);
  float acc = b1[o];
  #pragma unroll
  for (int c = 0; c < Cn; ++c)
    acc = fmaf(pooled[(b * Cn + c) * 9 + bin], w1[o * Cn + c], acc);
  g[idx] = 1.f / (1.f + expf(-acc));
}

// kernA: per (b,r): 18 fragments (t*2+h), each [kg(4)][m(16)][j(8)] bf16.
// value(b,r,t,h,kg,m,j) = kern(b, r, tap=t, c=kg*8+j, u=h*16+m)
__global__ void kern_kernel(const float* __restrict__ g, const float* __restrict__ w2,
                            const float* __restrict__ b2, short* __restrict__ kernA) {
  const int idx = blockIdx.x * 256 + threadIdx.x;
  if (idx >= Bn * 8 * 9 * 1024) return;
  const int j  = idx & 7;
  const int m  = (idx >> 3) & 15;
  const int kg = (idx >> 7) & 3;
  const int h  = (idx >> 9) & 1;
  const int t  = (idx >> 10) % 9;
  const int br = idx / 9216;
  const int r = br & 7, b = br >> 3;
  const int c = kg * 8 + j;
  const int u = h * 16 + m;
  const int jidx = u * 32 + c;                     // index within C*OUT group
  float acc = b2[r * 1024 + jidx];
  #pragma unroll
  for (int i = 0; i < 8; ++i)
    acc = fmaf(g[(b * 64 + r * 8 + i) * 9 + t], w2[(r * 1024 + jidx) * 8 + i], acc);
  kernA[idx] = (short)f2b(acc);
}

// wfA: 18 K-blocks (kb = tap*2+chalf) x 2 o-halves, each [kg][m][j] bf16.
__global__ void wf_kernel(const float* __restrict__ w_f, short* __restrict__ wfA) {
  int idx = blockIdx.x * 256 + threadIdx.x;
  if (idx >= 18432) return;
  const int j  = idx & 7;
  const int m  = (idx >> 3) & 15;
  const int kg = (idx >> 7) & 3;
  const int h  = (idx >> 9) & 1;
  const int kb = idx >> 10;        // 0..17
  const int tap = kb >> 1, ch = kb & 1;
  const int ci = ch * 32 + kg * 8 + j;
  const int o = h * 16 + m;
  wfA[idx] = (short)f2b(w_f[(o * 64 + ci) * 9 + tap]);
}

// ---------------- halo zero (interiors are fully overwritten every call) ----------------

__global__ void halo_kernel(uint4* __restrict__ inTp, uint4* __restrict__ catp) {
  const int idx = blockIdx.x * 256 + threadIdx.x;   // b*520 + i
  if (idx >= Bn * 520) return;
  const int b = idx / 520, i = idx % 520;
  int y, x;
  if (i < 130)      { y = 0;       x = i; }
  else if (i < 260) { y = 129;     x = i - 130; }
  else if (i < 390) { y = i - 260; x = 0; }
  else              { y = i - 390; x = 129; }
  const size_t pp = (size_t)(b * PW + y) * PW + x;
  const uint4 z = make_uint4(0u, 0u, 0u, 0u);
  #pragma unroll
  for (int q = 0; q < 4; ++q) inTp[pp * 4 + q] = z;
  #pragma unroll
  for (int q = 0; q < 8; ++q) catp[pp * 8 + q] = z;
}

// ---------------- input transpose to padded channel-last bf16 ----------------

__global__ __launch_bounds__(256) void tr_kernel(const float* __restrict__ in,
                                                 uint4* __restrict__ inTp) {
  __shared__ float lds[32][65];
  const int blk = blockIdx.x;          // b*256 + pixel-group
  const int b = blk >> 8;
  const int p0 = (blk & 255) * 64;
  const int tid = threadIdx.x;
  const int pl = tid & 63;
  const int c0 = tid >> 6;             // 0..3
  #pragma unroll
  for (int cc = 0; cc < 8; ++cc) {
    const int c = cc * 4 + c0;
    lds[c][pl] = in[(size_t)(b * 32 + c) * HW + p0 + pl];
  }
  __syncthreads();
  const int pw = tid >> 2;             // 0..63
  const int cg = (tid & 3) * 8;        // 0,8,16,24
  unsigned int w0 = (unsigned)f2b(lds[cg + 0][pw]) | ((unsigned)f2b(lds[cg + 1][pw]) << 16);
  unsigned int w1 = (unsigned)f2b(lds[cg + 2][pw]) | ((unsigned)f2b(lds[cg + 3][pw]) << 16);
  unsigned int w2 = (unsigned)f2b(lds[cg + 4][pw]) | ((unsigned)f2b(lds[cg + 5][pw]) << 16);
  unsigned int w3 = (unsigned)f2b(lds[cg + 6][pw]) | ((unsigned)f2b(lds[cg + 7][pw]) << 16);
  const int p = p0 + pw;
  const int y = p >> 7, x = p & 127;
  const size_t pp = (size_t)(b * PW + y + 1) * PW + (x + 1);
  inTp[pp * 4 + (tid & 3)] = make_uint4(w0, w1, w2, w3);
}

// ---------------- region selection ----------------

__global__ void rsel_kernel(const float* __restrict__ guide,
                            const float* __restrict__ w_spa, const float* __restrict__ b_spa,
                            const float* __restrict__ w_spec, const float* __restrict__ b_spec,
                            int* __restrict__ rsel) {
  const int idx = blockIdx.x * 256 + threadIdx.x;   // b*HW + p
  const int b = idx >> 14;
  const int p = idx & (HW - 1);
  float gv[Cn];
  const float* gp = guide + (size_t)b * Cn * HW + p;
  #pragma unroll
  for (int c = 0; c < Cn; ++c) gv[c] = gp[c * HW];
  int best1 = 0, best2 = 0;
  float bv1 = -1e30f, bv2 = -1e30f;
  for (int r = 0; r < Rn; ++r) {
    float v1 = b_spa[r], v2 = b_spec[r];
    #pragma unroll
    for (int c = 0; c < Cn; ++c) {
      v1 = fmaf(gv[c], w_spa[r * Cn + c], v1);
      v2 = fmaf(gv[c], w_spec[r * Cn + c], v2);
    }
    if (v1 > bv1) { bv1 = v1; best1 = r; }   // strict > keeps FIRST max (jnp.argmax)
    if (v2 > bv2) { bv2 = v2; best2 = r; }
  }
  rsel[idx] = best1 | (best2 << 8);
}

// ---------------- stage B: selected correlation conv via MFMA ----------------
// C[o(32), entry(16)] per group; A = generated weights, B = input pixels.

__global__ __launch_bounds__(256) void stageB_kernel(
    const char* __restrict__ inTp, const short* __restrict__ kernA,
    const int* __restrict__ rsel, char* __restrict__ catp) {
  const int id = blockIdx.x;
  const int chunk = id & 7, r = (id >> 3) & 7, b = id >> 6;  // chunk fastest -> XCD affinity
  const int pbase = chunk * 2048;
  __shared__ int lcount;
  __shared__ unsigned short list[4096];
  const int tid = threadIdx.x;
  if (tid == 0) lcount = 0;
  __syncthreads();
  const int* rs = rsel + b * HW + pbase;
  for (int i = tid; i < 2048; i += 256) {
    int v = rs[i];
    if ((v & 255) == r) { int k = atomicAdd(&lcount, 1); list[k] = (unsigned short)i; }
    if ((v >> 8) == r)  { int k = atomicAdd(&lcount, 1); list[k] = (unsigned short)(i | 2048); }
  }
  __syncthreads();
  const int cnt = lcount;
  const int lane = tid & 63, wid = tid >> 6;
  const int l15 = lane & 15, kg = lane >> 4;

  // preload the 18 weight A-fragments (uniform per block)
  short8 aw[18];
  {
    const short* kb = kernA + (size_t)(b * 8 + r) * 18 * 512;
    #pragma unroll
    for (int f = 0; f < 18; ++f)
      aw[f] = *(const short8*)(kb + f * 512 + kg * 128 + l15 * 8);
  }

  for (int g = wid; g * 16 < cnt; g += 4) {
    const int e16 = g * 16 + l15;
    const bool ev = e16 < cnt;
    const int ent = list[ev ? e16 : 0];
    const int p = pbase + (ent & 2047);
    const int which = ent >> 11;
    const int y = p >> 7, x = p & 127;
    const size_t pp = (size_t)(b * PW + y + 1) * PW + (x + 1);
    const char* base = inTp + pp * 64 + kg * 16;
    floatx4 acc0 = {0.f, 0.f, 0.f, 0.f}, acc1 = {0.f, 0.f, 0.f, 0.f};
    #pragma unroll
    for (int t = 0; t < 9; ++t) {
      const int dy = t / 3 - 1, dx = t % 3 - 1;
      const short8 bx = *(const short8*)(base + (dy * PW + dx) * 64);
      acc0 = __builtin_amdgcn_mfma_f32_16x16x32_bf16(aw[t * 2 + 0], bx, acc0, 0, 0, 0);
      acc1 = __builtin_amdgcn_mfma_f32_16x16x32_bf16(aw[t * 2 + 1], bx, acc1, 0, 0, 0);
    }
    if (ev) {
      char* op = catp + pp * 128 + which * 64 + kg * 8;
      uint2 v0, v1;
      v0.x = (unsigned)f2b(acc0[0]) | ((unsigned)f2b(acc0[1]) << 16);
      v0.y = (unsigned)f2b(acc0[2]) | ((unsigned)f2b(acc0[3]) << 16);
      v1.x = (unsigned)f2b(acc1[0]) | ((unsigned)f2b(acc1[1]) << 16);
      v1.y = (unsigned)f2b(acc1[2]) | ((unsigned)f2b(acc1[3]) << 16);
      *(uint2*)op = v0;
      *(uint2*)(op + 32) = v1;
    }
  }
}

// ---------------- stage C: fusion conv via MFMA + bias + residual ----------------

__global__ __launch_bounds__(256, 4) void stageC_kernel(
    const char* __restrict__ catp, const short* __restrict__ wfA,
    const float* __restrict__ b_f, const float* __restrict__ in,
    float* __restrict__ out) {
  __shared__ short lwf[18432];
  const int tid = threadIdx.x;
  {
    const uint4* src = (const uint4*)wfA;
    uint4* dst = (uint4*)lwf;
    #pragma unroll
    for (int i = 0; i < 9; ++i)
      dst[i * 256 + tid] = src[i * 256 + tid];
  }
  __syncthreads();
  const int id = blockIdx.x;
  const int b = id >> 6, seg = id & 63;
  const int lane = tid & 63, wid = tid >> 6;
  const int l15 = lane & 15, kg = lane >> 4;
  const int pix = seg * 256 + wid * 64 + l15;     // + q*16

  const char* bq[4];
  #pragma unroll
  for (int q = 0; q < 4; ++q) {
    const int p = pix + q * 16;
    const int y = p >> 7, x = p & 127;
    bq[q] = catp + ((size_t)(b * PW + y + 1) * PW + (x + 1)) * 128 + kg * 16;
  }
  floatx4 acc[2][4] = {};
  #pragma unroll 3
  for (int kb = 0; kb < 18; ++kb) {
    const int tap = kb >> 1, ch = kb & 1;
    const int dy = tap / 3 - 1, dx = tap % 3 - 1;
    const int goff = (dy * PW + dx) * 128 + ch * 64;
    const short8 a0 = *(const short8*)&lwf[(kb * 2 + 0) * 512 + kg * 128 + l15 * 8];
    const short8 a1 = *(const short8*)&lwf[(kb * 2 + 1) * 512 + kg * 128 + l15 * 8];
    #pragma unroll
    for (int q = 0; q < 4; ++q) {
      const short8 bx = *(const short8*)(bq[q] + goff);
      acc[0][q] = __builtin_amdgcn_mfma_f32_16x16x32_bf16(a0, bx, acc[0][q], 0, 0, 0);
      acc[1][q] = __builtin_amdgcn_mfma_f32_16x16x32_bf16(a1, bx, acc[1][q], 0, 0, 0);
    }
  }
  #pragma unroll
  for (int h = 0; h < 2; ++h) {
    const int o0 = h * 16 + kg * 4;
    #pragma unroll
    for (int q = 0; q < 4; ++q) {
      const int p = pix + q * 16;
      #pragma unroll
      for (int reg = 0; reg < 4; ++reg) {
        const size_t oi = (size_t)(b * 32 + o0 + reg) * HW + p;
        out[oi] = acc[h][q][reg] + b_f[o0 + reg] + in[oi];
      }
    }
  }
}

// ---------------- launcher ----------------

extern "C" void kernel_launch(void* const* d_in, const int* in_sizes, int n_in,
                              void* d_out, int out_size, void* d_ws, size_t ws_size,
                              hipStream_t stream) {
  const float* input  = (const float*)d_in[0];
  const float* guide  = (const float*)d_in[1];
  const float* w1     = (const float*)d_in[2];
  const float* b1     = (const float*)d_in[3];
  const float* w2     = (const float*)d_in[4];
  const float* b2     = (const float*)d_in[5];
  const float* w_spa  = (const float*)d_in[6];
  const float* b_spa  = (const float*)d_in[7];
  const float* w_spec = (const float*)d_in[8];
  const float* b_spec = (const float*)d_in[9];
  const float* w_f    = (const float*)d_in[10];
  const float* b_f    = (const float*)d_in[11];
  float* out = (float*)d_out;

  char* ws = (char*)d_ws;
  float* pooled = (float*)(ws + OFF_POOLED);
  float* g      = (float*)(ws + OFF_G);
  short* kernA  = (short*)(ws + OFF_KERNA);
  short* wfA    = (short*)(ws + OFF_WFA);
  int*   rsel   = (int*)(ws + OFF_RSEL);
  uint4* inTp   = (uint4*)(ws + OFF_INTP);
  char*  catp   = (char*)(ws + OFF_CATP);

  pool_kernel<<<Bn * Cn * 9, 64, 0, stream>>>(input, pooled);
  g_kernel<<<(Bn * 64 * 9 + 255) / 256, 256, 0, stream>>>(pooled, w1, b1, g);
  kern_kernel<<<Bn * 8 * 9 * 1024 / 256, 256, 0, stream>>>(g, w2, b2, kernA);
  wf_kernel<<<72, 256, 0, stream>>>(w_f, wfA);
  halo_kernel<<<(Bn * 520 + 255) / 256, 256, 0, stream>>>(inTp, (uint4*)catp);
  tr_kernel<<<Bn * 256, 256, 0, stream>>>(input, inTp);
  rsel_kernel<<<Bn * HW / 256, 256, 0, stream>>>(guide, w_spa, b_spa, w_spec, b_spec, rsel);
  stageB_kernel<<<1024, 256, 0, stream>>>((const char*)inTp, kernA, rsel, catp);
  stageC_kernel<<<1024, 256, 0, stream>>>(catp, wfA, b_f, input, out);
}

// Round 6
// 252.529 us; speedup vs baseline: 2.8233x; 1.0016x over previous
//
#include <hip/hip_runtime.h>
#include <hip/hip_bf16.h>
#include <math.h>

#define Bn 16
#define Cn 32
#define Hn 128
#define Wn 128
#define HW (Hn*Wn)
#define Rn 8
#define OUTn 32
#define PW 130           // padded width/height (1-px halo)

// ws layout (byte offsets, all 16B-aligned)
#define OFF_POOLED 0u            // 4608 f
#define OFF_G      18432u        // 9216 f
#define OFF_KERNA  55296u        // 1179648 bf16  A-frag layout [b][r][t*2+h][kg][m][j]
#define OFF_WFA    2414592u      // 18432 bf16    A-frag layout [kb*2+h][kg][m][j]
#define OFF_RSEL   2451456u      // 262144 int
#define OFF_INTP   3500032u      // 16*16900 px * 64B  bf16 channel-last, padded
#define OFF_CATP   20805632u     // 16*16900 px * 128B bf16 channel-last, padded
// ends 55,416,832

typedef __attribute__((ext_vector_type(8))) short short8;
typedef __attribute__((ext_vector_type(4))) float floatx4;

static __device__ __forceinline__ unsigned short f2b(float f) {
  __hip_bfloat16 h = __float2bfloat16(f);
  return *reinterpret_cast<unsigned short*>(&h);
}

// ---------------- stage A: dynamic kernel generation ----------------

// one wave per (b, c, bin): no LDS, no barriers
__global__ __launch_bounds__(64) void pool_kernel(const float* __restrict__ in,
                                                  float* __restrict__ pooled) {
  const int blk = blockIdx.x;          // bc*9 + bin
  const int bin = blk % 9, bc = blk / 9;
  const int bi = bin / 3, bj = bin % 3;
  const int s0[3] = {0, 42, 85};
  const int e0[3] = {43, 86, 128};
  const int rs = s0[bi], re = e0[bi];
  const int cs = s0[bj], ce = e0[bj];
  const int n = (re - rs) * (ce - cs);
  const float* img = in + (size_t)bc * HW;
  float acc = 0.f;
  for (int y = rs; y < re; ++y)
    for (int x = cs + (int)threadIdx.x; x < ce; x += 64)
      acc += img[y * Wn + x];
  #pragma unroll
  for (int off = 32; off > 0; off >>= 1) acc += __shfl_down(acc, off, 64);
  if (threadIdx.x == 0) pooled[bc * 9 + bin] = acc / (float)n;
}

__global__ void g_kernel(const float* __restrict__ pooled, const float* __restrict__ w1,
                         const float* __restrict__ b1, float* __restrict__ g) {
  const int idx = blockIdx.x * 256 + threadIdx.x;   // (b*64 + o64)*9 + bin
  if (idx >= Bn * 64 * 9) return;
  const int bin = idx % 9;
  const int o = (idx / 9) % 64;
  const int b = idx / (9 * 64);
  float acc = b1[o];
  #pragma unroll
  for (int c = 0; c < Cn; ++c)
    acc = fmaf(pooled[(b * Cn + c) * 9 + bin], w1[o * Cn + c], acc);
  g[idx] = 1.f / (1.f + expf(-acc));
}

// kernA: per (b,r): 18 fragments (t*2+h), each [kg(4)][m(16)][j(8)] bf16.
// value(b,r,t,h,kg,m,j) = kern(b, r, tap=t, c=kg*8+j, u=h*16+m)
__global__ void kern_kernel(const float* __restrict__ g, const float* __restrict__ w2,
                            const float* __restrict__ b2, short* __restrict__ kernA) {
  const int idx = blockIdx.x * 256 + threadIdx.x;
  if (idx >= Bn * 8 * 9 * 1024) return;
  const int j  = idx & 7;
  const int m  = (idx >> 3) & 15;
  const int kg = (idx >> 7) & 3;
  const int h  = (idx >> 9) & 1;
  const int t  = (idx >> 10) % 9;
  const int br = idx / 9216;
  const int r = br & 7, b = br >> 3;
  const int c = kg * 8 + j;
  const int u = h * 16 + m;
  const int jidx = u * 32 + c;                     // index within C*OUT group
  float acc = b2[r * 1024 + jidx];
  #pragma unroll
  for (int i = 0; i < 8; ++i)
    acc = fmaf(g[(b * 64 + r * 8 + i) * 9 + t], w2[(r * 1024 + jidx) * 8 + i], acc);
  kernA[idx] = (short)f2b(acc);
}

// wfA: 18 K-blocks (kb = tap*2+chalf) x 2 o-halves, each [kg][m][j] bf16.
__global__ void wf_kernel(const float* __restrict__ w_f, short* __restrict__ wfA) {
  int idx = blockIdx.x * 256 + threadIdx.x;
  if (idx >= 18432) return;
  const int j  = idx & 7;
  const int m  = (idx >> 3) & 15;
  const int kg = (idx >> 7) & 3;
  const int h  = (idx >> 9) & 1;
  const int kb = idx >> 10;        // 0..17
  const int tap = kb >> 1, ch = kb & 1;
  const int ci = ch * 32 + kg * 8 + j;
  const int o = h * 16 + m;
  wfA[idx] = (short)f2b(w_f[(o * 64 + ci) * 9 + tap]);
}

// ---------------- halo zero (interiors are fully overwritten every call) ----------------

__global__ void halo_kernel(uint4* __restrict__ inTp, uint4* __restrict__ catp) {
  const int idx = blockIdx.x * 256 + threadIdx.x;   // b*520 + i
  if (idx >= Bn * 520) return;
  const int b = idx / 520, i = idx % 520;
  int y, x;
  if (i < 130)      { y = 0;       x = i; }
  else if (i < 260) { y = 129;     x = i - 130; }
  else if (i < 390) { y = i - 260; x = 0; }
  else              { y = i - 390; x = 129; }
  const size_t pp = (size_t)(b * PW + y) * PW + x;
  const uint4 z = make_uint4(0u, 0u, 0u, 0u);
  #pragma unroll
  for (int q = 0; q < 4; ++q) inTp[pp * 4 + q] = z;
  #pragma unroll
  for (int q = 0; q < 8; ++q) catp[pp * 8 + q] = z;
}

// ---------------- input transpose to padded channel-last bf16 ----------------

__global__ __launch_bounds__(256) void tr_kernel(const float* __restrict__ in,
                                                 uint4* __restrict__ inTp) {
  __shared__ float lds[32][65];
  const int blk = blockIdx.x;          // b*256 + pixel-group
  const int b = blk >> 8;
  const int p0 = (blk & 255) * 64;
  const int tid = threadIdx.x;
  const int pl = tid & 63;
  const int c0 = tid >> 6;             // 0..3
  #pragma unroll
  for (int cc = 0; cc < 8; ++cc) {
    const int c = cc * 4 + c0;
    lds[c][pl] = in[(size_t)(b * 32 + c) * HW + p0 + pl];
  }
  __syncthreads();
  const int pw = tid >> 2;             // 0..63
  const int cg = (tid & 3) * 8;        // 0,8,16,24
  unsigned int w0 = (unsigned)f2b(lds[cg + 0][pw]) | ((unsigned)f2b(lds[cg + 1][pw]) << 16);
  unsigned int w1 = (unsigned)f2b(lds[cg + 2][pw]) | ((unsigned)f2b(lds[cg + 3][pw]) << 16);
  unsigned int w2 = (unsigned)f2b(lds[cg + 4][pw]) | ((unsigned)f2b(lds[cg + 5][pw]) << 16);
  unsigned int w3 = (unsigned)f2b(lds[cg + 6][pw]) | ((unsigned)f2b(lds[cg + 7][pw]) << 16);
  const int p = p0 + pw;
  const int y = p >> 7, x = p & 127;
  const size_t pp = (size_t)(b * PW + y + 1) * PW + (x + 1);
  inTp[pp * 4 + (tid & 3)] = make_uint4(w0, w1, w2, w3);
}

// ---------------- region selection ----------------

__global__ void rsel_kernel(const float* __restrict__ guide,
                            const float* __restrict__ w_spa, const float* __restrict__ b_spa,
                            const float* __restrict__ w_spec, const float* __restrict__ b_spec,
                            int* __restrict__ rsel) {
  const int idx = blockIdx.x * 256 + threadIdx.x;   // b*HW + p
  const int b = idx >> 14;
  const int p = idx & (HW - 1);
  float gv[Cn];
  const float* gp = guide + (size_t)b * Cn * HW + p;
  #pragma unroll
  for (int c = 0; c < Cn; ++c) gv[c] = gp[c * HW];
  int best1 = 0, best2 = 0;
  float bv1 = -1e30f, bv2 = -1e30f;
  for (int r = 0; r < Rn; ++r) {
    float v1 = b_spa[r], v2 = b_spec[r];
    #pragma unroll
    for (int c = 0; c < Cn; ++c) {
      v1 = fmaf(gv[c], w_spa[r * Cn + c], v1);
      v2 = fmaf(gv[c], w_spec[r * Cn + c], v2);
    }
    if (v1 > bv1) { bv1 = v1; best1 = r; }   // strict > keeps FIRST max (jnp.argmax)
    if (v2 > bv2) { bv2 = v2; best2 = r; }
  }
  rsel[idx] = best1 | (best2 << 8);
}

// ---------------- stage B: selected correlation conv via MFMA ----------------
// C[o(32), entry(16)] per group; A = generated weights, B = input pixels.

__global__ __launch_bounds__(256) void stageB_kernel(
    const char* __restrict__ inTp, const short* __restrict__ kernA,
    const int* __restrict__ rsel, char* __restrict__ catp) {
  const int id = blockIdx.x;
  const int chunk = id & 7, r = (id >> 3) & 7, b = id >> 6;  // chunk fastest -> XCD affinity
  const int pbase = chunk * 2048;
  __shared__ int lcount;
  __shared__ unsigned short list[4096];
  const int tid = threadIdx.x;
  if (tid == 0) lcount = 0;
  __syncthreads();
  const int* rs = rsel + b * HW + pbase;
  for (int i = tid; i < 2048; i += 256) {
    int v = rs[i];
    if ((v & 255) == r) { int k = atomicAdd(&lcount, 1); list[k] = (unsigned short)i; }
    if ((v >> 8) == r)  { int k = atomicAdd(&lcount, 1); list[k] = (unsigned short)(i | 2048); }
  }
  __syncthreads();
  const int cnt = lcount;
  const int lane = tid & 63, wid = tid >> 6;
  const int l15 = lane & 15, kg = lane >> 4;

  // preload the 18 weight A-fragments (uniform per block)
  short8 aw[18];
  {
    const short* kb = kernA + (size_t)(b * 8 + r) * 18 * 512;
    #pragma unroll
    for (int f = 0; f < 18; ++f)
      aw[f] = *(const short8*)(kb + f * 512 + kg * 128 + l15 * 8);
  }

  for (int g = wid; g * 16 < cnt; g += 4) {
    const int e16 = g * 16 + l15;
    const bool ev = e16 < cnt;
    const int ent = list[ev ? e16 : 0];
    const int p = pbase + (ent & 2047);
    const int which = ent >> 11;
    const int y = p >> 7, x = p & 127;
    const size_t pp = (size_t)(b * PW + y + 1) * PW + (x + 1);
    const char* base = inTp + pp * 64 + kg * 16;
    floatx4 acc0 = {0.f, 0.f, 0.f, 0.f}, acc1 = {0.f, 0.f, 0.f, 0.f};
    #pragma unroll
    for (int t = 0; t < 9; ++t) {
      const int dy = t / 3 - 1, dx = t % 3 - 1;
      const short8 bx = *(const short8*)(base + (dy * PW + dx) * 64);
      acc0 = __builtin_amdgcn_mfma_f32_16x16x32_bf16(aw[t * 2 + 0], bx, acc0, 0, 0, 0);
      acc1 = __builtin_amdgcn_mfma_f32_16x16x32_bf16(aw[t * 2 + 1], bx, acc1, 0, 0, 0);
    }
    if (ev) {
      char* op = catp + pp * 128 + which * 64 + kg * 8;
      uint2 v0, v1;
      v0.x = (unsigned)f2b(acc0[0]) | ((unsigned)f2b(acc0[1]) << 16);
      v0.y = (unsigned)f2b(acc0[2]) | ((unsigned)f2b(acc0[3]) << 16);
      v1.x = (unsigned)f2b(acc1[0]) | ((unsigned)f2b(acc1[1]) << 16);
      v1.y = (unsigned)f2b(acc1[2]) | ((unsigned)f2b(acc1[3]) << 16);
      *(uint2*)op = v0;
      *(uint2*)(op + 32) = v1;
    }
  }
}

// ---------------- stage C: fusion conv via MFMA + bias + residual ----------------
// XCD-chunked swizzle: XCD(hw_bid)=bid%8 (round-robin); give each XCD 128
// CONTIGUOUS row-strips (= 2 whole batches) so adjacent strips' shared catp
// rows hit the same L2 instead of being re-fetched from HBM per XCD.

__global__ __launch_bounds__(256, 4) void stageC_kernel(
    const char* __restrict__ catp, const short* __restrict__ wfA,
    const float* __restrict__ b_f, const float* __restrict__ in,
    float* __restrict__ out) {
  __shared__ short lwf[18432];
  const int tid = threadIdx.x;
  {
    const uint4* src = (const uint4*)wfA;
    uint4* dst = (uint4*)lwf;
    #pragma unroll
    for (int i = 0; i < 9; ++i)
      dst[i * 256 + tid] = src[i * 256 + tid];
  }
  __syncthreads();
  const int id = (blockIdx.x & 7) * 128 + (blockIdx.x >> 3);   // T1 XCD swizzle
  const int b = id >> 6, seg = id & 63;
  const int lane = tid & 63, wid = tid >> 6;
  const int l15 = lane & 15, kg = lane >> 4;
  const int pix = seg * 256 + wid * 64 + l15;     // + q*16

  const char* bq[4];
  #pragma unroll
  for (int q = 0; q < 4; ++q) {
    const int p = pix + q * 16;
    const int y = p >> 7, x = p & 127;
    bq[q] = catp + ((size_t)(b * PW + y + 1) * PW + (x + 1)) * 128 + kg * 16;
  }
  floatx4 acc[2][4] = {};
  #pragma unroll
  for (int kb = 0; kb < 18; ++kb) {
    const int tap = kb >> 1, ch = kb & 1;
    const int dy = tap / 3 - 1, dx = tap % 3 - 1;
    const int goff = (dy * PW + dx) * 128 + ch * 64;
    const short8 a0 = *(const short8*)&lwf[(kb * 2 + 0) * 512 + kg * 128 + l15 * 8];
    const short8 a1 = *(const short8*)&lwf[(kb * 2 + 1) * 512 + kg * 128 + l15 * 8];
    #pragma unroll
    for (int q = 0; q < 4; ++q) {
      const short8 bx = *(const short8*)(bq[q] + goff);
      acc[0][q] = __builtin_amdgcn_mfma_f32_16x16x32_bf16(a0, bx, acc[0][q], 0, 0, 0);
      acc[1][q] = __builtin_amdgcn_mfma_f32_16x16x32_bf16(a1, bx, acc[1][q], 0, 0, 0);
    }
  }
  #pragma unroll
  for (int h = 0; h < 2; ++h) {
    const int o0 = h * 16 + kg * 4;
    #pragma unroll
    for (int q = 0; q < 4; ++q) {
      const int p = pix + q * 16;
      #pragma unroll
      for (int reg = 0; reg < 4; ++reg) {
        const size_t oi = (size_t)(b * 32 + o0 + reg) * HW + p;
        out[oi] = acc[h][q][reg] + b_f[o0 + reg] + in[oi];
      }
    }
  }
}

// ---------------- launcher ----------------

extern "C" void kernel_launch(void* const* d_in, const int* in_sizes, int n_in,
                              void* d_out, int out_size, void* d_ws, size_t ws_size,
                              hipStream_t stream) {
  const float* input  = (const float*)d_in[0];
  const float* guide  = (const float*)d_in[1];
  const float* w1     = (const float*)d_in[2];
  const float* b1     = (const float*)d_in[3];
  const float* w2     = (const float*)d_in[4];
  const float* b2     = (const float*)d_in[5];
  const float* w_spa  = (const float*)d_in[6];
  const float* b_spa  = (const float*)d_in[7];
  const float* w_spec = (const float*)d_in[8];
  const float* b_spec = (const float*)d_in[9];
  const float* w_f    = (const float*)d_in[10];
  const float* b_f    = (const float*)d_in[11];
  float* out = (float*)d_out;

  char* ws = (char*)d_ws;
  float* pooled = (float*)(ws + OFF_POOLED);
  float* g      = (float*)(ws + OFF_G);
  short* kernA  = (short*)(ws + OFF_KERNA);
  short* wfA    = (short*)(ws + OFF_WFA);
  int*   rsel   = (int*)(ws + OFF_RSEL);
  uint4* inTp   = (uint4*)(ws + OFF_INTP);
  char*  catp   = (char*)(ws + OFF_CATP);

  pool_kernel<<<Bn * Cn * 9, 64, 0, stream>>>(input, pooled);
  g_kernel<<<(Bn * 64 * 9 + 255) / 256, 256, 0, stream>>>(pooled, w1, b1, g);
  kern_kernel<<<Bn * 8 * 9 * 1024 / 256, 256, 0, stream>>>(g, w2, b2, kernA);
  wf_kernel<<<72, 256, 0, stream>>>(w_f, wfA);
  halo_kernel<<<(Bn * 520 + 255) / 256, 256, 0, stream>>>(inTp, (uint4*)catp);
  tr_kernel<<<Bn * 256, 256, 0, stream>>>(input, inTp);
  rsel_kernel<<<Bn * HW / 256, 256, 0, stream>>>(guide, w_spa, b_spa, w_spec, b_spec, rsel);
  stageB_kernel<<<1024, 256, 0, stream>>>((const char*)inTp, kernA, rsel, catp);
  stageC_kernel<<<1024, 256, 0, stream>>>(catp, wfA, b_f, input, out);
}